// Round 7
// baseline (222.337 us; speedup 1.0000x reference)
//
#include <hip/hip_runtime.h>
#include <hip/hip_bf16.h>
#include <stdint.h>

#define B_  2
#define T_  2048
#define D_  1024
#define H_  16
#define KS  64
#define M_  (B_*T_)    // 4096

typedef unsigned short u16;
typedef __bf16 bf16x8 __attribute__((ext_vector_type(8)));
typedef __bf16 bf16x4 __attribute__((ext_vector_type(4)));
typedef float  f32x4  __attribute__((ext_vector_type(4)));

#define AS1 __attribute__((address_space(1)))
#define AS3 __attribute__((address_space(3)))

__device__ inline u16 f2bf(float x){
  union { float f; uint32_t u; } v; v.f = x;
  uint32_t r = (v.u + 0x7fffu + ((v.u >> 16) & 1u)) >> 16;
  return (u16)r;
}

__device__ inline void gl_lds16(const u16* g, u16* l){
  __builtin_amdgcn_global_load_lds((AS1 void*)(const_cast<u16*>(g)),
                                   (AS3 void*)l, 16, 0, 0);
}

// ---------------- x fp32 -> bf16 ----------------
__global__ __launch_bounds__(256) void k_cvt_x(const float* __restrict__ x,
                                               u16* __restrict__ xb){
  int i = blockIdx.x * 256 + threadIdx.x;
  float4 v = ((const float4*)x)[i];
  ushort4 o;
  o.x = f2bf(v.x); o.y = f2bf(v.y); o.z = f2bf(v.z); o.w = f2bf(v.w);
  ((ushort4*)xb)[i] = o;
}

// ---------------- W [K,N] fp32 -> WT [N,K] bf16 (all 4 weights) ----------------
__global__ __launch_bounds__(256) void k_tconv_w(const float* __restrict__ W0,
                                                 const float* __restrict__ W1,
                                                 const float* __restrict__ W2,
                                                 const float* __restrict__ W3,
                                                 u16* __restrict__ out){
  const float* W = (blockIdx.z==0)?W0:(blockIdx.z==1)?W1:(blockIdx.z==2)?W2:W3;
  u16* o = out + (size_t)blockIdx.z * 1024 * 1024;
  __shared__ float tile[32][33];
  int tx = threadIdx.x, ty = threadIdx.y;          // 32 x 8
  int kb = blockIdx.y * 32, nb = blockIdx.x * 32;
  for(int i=0;i<4;i++) tile[ty+8*i][tx] = W[(size_t)(kb+ty+8*i)*1024 + nb+tx];
  __syncthreads();
  for(int i=0;i<4;i++){
    int n = nb + ty + 8*i;
    o[(size_t)n*1024 + kb + tx] = f2bf(tile[tx][ty+8*i]);
  }
}

// ---------------- fused QKV GEMM: [4096,1024] x WT[1024,1024] + bias ----------------
// Q,K computed as C^T (reg-axis = n = kk) -> packed bf16x4 stores to [B,H,T,64];
// V computed normal (reg-axis = m = t)   -> packed bf16x4 stores to VT [B*H,64,T].
// Q pre-scaled by (1/8)*log2(e) for exp2 softmax.
__global__ __launch_bounds__(256) void k_gemm_qkv(const u16* __restrict__ xb,
                                                  const u16* __restrict__ wt,
                                                  const float* __restrict__ bq,
                                                  const float* __restrict__ bk,
                                                  const float* __restrict__ bv,
                                                  u16* __restrict__ qkv,
                                                  u16* __restrict__ vt){
  int widx = blockIdx.x >> 3;                 // 0..2 : q,k,v
  int n0   = (blockIdx.x & 7) * 128;
  int m0   = blockIdx.y * 128;
  const u16* BT = wt + (size_t)widx * (1024*1024);
  const float* bias = (widx==0)?bq:(widx==1)?bk:bv;
  u16* out = qkv + (size_t)widx * (4*1024*1024);
  float oscale = (widx==0) ? 0.125f * 1.44269504088896f : 1.0f;

  __shared__ u16 Asm[128*64];
  __shared__ u16 Bsm[128*64];
  int t = threadIdx.x;
  int lane = t & 63, w = t >> 6, wm = w >> 1, wn = w & 1;
  int l15 = lane & 15, l4 = lane >> 4;
  f32x4 zero = {0.f,0.f,0.f,0.f};
  f32x4 acc[4][4];
  for(int i=0;i<4;i++) for(int j=0;j<4;j++) acc[i][j] = zero;
  int srow = t >> 3, schunk = t & 7;

  for(int kt=0; kt<16; ++kt){
    __syncthreads();
    int kb = kt * 64;
    for(int i=0;i<4;i++){
      int row = i*32 + srow;
      int gch = schunk ^ (row & 7);           // pre-swizzled global source (T2)
      gl_lds16(xb + (size_t)(m0+row)*1024 + kb + gch*8, Asm + row*64 + schunk*8);
      gl_lds16(BT + (size_t)(n0+row)*1024 + kb + gch*8, Bsm + row*64 + schunk*8);
    }
    __syncthreads();
    for(int c=0;c<2;c++){
      bf16x8 af[4], bfr[4];
      for(int mt=0;mt<4;mt++){
        int row = wm*64 + mt*16 + l15;
        int idx = (row*64 + c*32 + l4*8) ^ ((row & 7) << 3);
        af[mt] = *(const bf16x8*)(Asm + idx);
      }
      for(int nt=0;nt<4;nt++){
        int row = wn*64 + nt*16 + l15;
        int idx = (row*64 + c*32 + l4*8) ^ ((row & 7) << 3);
        bfr[nt] = *(const bf16x8*)(Bsm + idx);
      }
      if(widx < 2){
        // C^T: reg-axis = n (kk), col = m (t)
        for(int mt=0;mt<4;mt++)
          for(int nt=0;nt<4;nt++)
            acc[mt][nt] = __builtin_amdgcn_mfma_f32_16x16x32_bf16(bfr[nt], af[mt], acc[mt][nt], 0,0,0);
      } else {
        // normal: reg-axis = m (t), col = n (kk)
        for(int mt=0;mt<4;mt++)
          for(int nt=0;nt<4;nt++)
            acc[mt][nt] = __builtin_amdgcn_mfma_f32_16x16x32_bf16(af[mt], bfr[nt], acc[mt][nt], 0,0,0);
      }
    }
  }
  if(widx == 2){
    // V epilogue: write transposed directly -> VT [B*H, 64, T], packed 4-t stores
    for(int nt=0;nt<4;nt++){
      int nbase = n0 + wn*64 + nt*16 + l15;
      float bv_ = bias[nbase];
      int h = nbase >> 6, kk = nbase & 63;
      for(int mt=0;mt<4;mt++){
        int m = m0 + wm*64 + mt*16 + l4*4;    // 4 consecutive t
        int b = m >> 11, tt = m & 2047;
        bf16x4 pk;
        for(int r=0;r<4;r++) pk[r] = (__bf16)(acc[mt][nt][r] + bv_);
        *(bf16x4*)(vt + (((size_t)(b*H_ + h)*64 + kk)*T_) + tt) = pk;
      }
    }
  } else {
    // Q/K epilogue (C^T): 4 consecutive kk per lane -> packed bf16x4 to [B,H,T,64]
    for(int nt=0;nt<4;nt++){
      int nb = n0 + wn*64 + nt*16 + l4*4;
      float4 b4 = *(const float4*)&bias[nb];
      int h = nb >> 6, kk = nb & 63;
      for(int mt=0;mt<4;mt++){
        int m = m0 + wm*64 + mt*16 + l15;
        int b = m >> 11, tt = m & 2047;
        bf16x4 pk;
        pk[0] = (__bf16)((acc[mt][nt][0] + b4.x) * oscale);
        pk[1] = (__bf16)((acc[mt][nt][1] + b4.y) * oscale);
        pk[2] = (__bf16)((acc[mt][nt][2] + b4.z) * oscale);
        pk[3] = (__bf16)((acc[mt][nt][3] + b4.w) * oscale);
        *(bf16x4*)(out + (((size_t)(b*H_ + h)*T_ + tt) << 6) + kk) = pk;
      }
    }
  }
}

// ---------------- flash attention (swapped-QK, O^T; ones-trick denominator) ----------------
// launch_bounds(256,3): LDS caps occupancy at 3-4 blocks/CU anyway — give the
// allocator ~170 VGPRs so swizzled LDS addresses hoist out of the loop.
// 2-tile unrolled loop -> compile-time `cur` -> fully invariant addresses.
__global__ __launch_bounds__(256, 3) void k_attn(const u16* __restrict__ Q,
                                                 const u16* __restrict__ Kg,
                                                 const u16* __restrict__ VT,
                                                 u16* __restrict__ attn_out){
  int bx = blockIdx.x;
  int qt = bx & 31, h = (bx >> 5) & 15, b = bx >> 9;
  int bh = b*H_ + h;
  const u16* Qh = Q  + (size_t)bh * T_ * 64;
  const u16* Kh = Kg + (size_t)bh * T_ * 64;
  const u16* Vh = VT + (size_t)bh * 64 * T_;
  __shared__ u16 Ksm[2][64*64];
  __shared__ u16 Vsm[2][64*64];
  __shared__ u16 Psm[4][16*64];
  int t = threadIdx.x, lane = t & 63, w = t >> 6;
  int l15 = lane & 15, l4 = lane >> 4;

  // Q fragments (B operand; cols q = l15), held all kernel
  bf16x8 qf[2];
  int qrow = qt*64 + w*16 + l15;
  for(int c=0;c<2;c++)
    qf[c] = *(const bf16x8*)(Qh + (size_t)qrow*64 + c*32 + l4*8);

  bf16x8 ones;
  for(int j=0;j<8;j++) ones[j] = (__bf16)1.0f;

  f32x4 zero = {0.f,0.f,0.f,0.f};
  f32x4 accT[4];                       // O^T: row d = g*16+l4*4+r, col q = l15
  for(int g=0;g<4;g++) accT[g] = zero;
  f32x4 accL = zero;                   // softmax denominator (ones-row MFMA)
  float m_r = -3.0e38f;                // per-lane running max for q = l15

  int srow = t >> 3, schunk = t & 7;
  int gchS = schunk ^ (srow & 7);      // staging swizzle chunk (rows srow, srow+32 share low-3 bits)

  // prologue: stage tile 0
  gl_lds16(Kh + (size_t)srow*64      + gchS*8, &Ksm[0][srow*64      + schunk*8]);
  gl_lds16(Kh + (size_t)(srow+32)*64 + gchS*8, &Ksm[0][(srow+32)*64 + schunk*8]);
  gl_lds16(Vh + (size_t)srow*T_      + gchS*8, &Vsm[0][srow*64      + schunk*8]);
  gl_lds16(Vh + (size_t)(srow+32)*T_ + gchS*8, &Vsm[0][(srow+32)*64 + schunk*8]);
  __syncthreads();

  auto body = [&](int tile, int cur){
    // issue next tile into the other buffer (hidden under compute)
    if(tile+1 < 32){
      int kvb = (tile+1)*64;
      gl_lds16(Kh + (size_t)(kvb+srow)*64    + gchS*8, &Ksm[cur^1][srow*64      + schunk*8]);
      gl_lds16(Kh + (size_t)(kvb+srow+32)*64 + gchS*8, &Ksm[cur^1][(srow+32)*64 + schunk*8]);
      gl_lds16(Vh + (size_t)srow*T_      + kvb + gchS*8, &Vsm[cur^1][srow*64      + schunk*8]);
      gl_lds16(Vh + (size_t)(srow+32)*T_ + kvb + gchS*8, &Vsm[cur^1][(srow+32)*64 + schunk*8]);
    }

    // S^T = K · Q^T : s[g] row = k = g*16 + l4*4 + r, col = q = l15
    f32x4 s[4];
    for(int g=0;g<4;g++) s[g] = zero;
    __builtin_amdgcn_s_setprio(1);
    for(int c=0;c<2;c++){
      for(int g=0;g<4;g++){
        int row = g*16 + l15;
        int idx = (row*64 + c*32 + l4*8) ^ ((row & 7) << 3);
        bf16x8 kf = *(const bf16x8*)(&Ksm[cur][idx]);
        s[g] = __builtin_amdgcn_mfma_f32_16x16x32_bf16(kf, qf[c], s[g], 0,0,0);
      }
    }
    __builtin_amdgcn_s_setprio(0);

    // per-lane max over 16 in-register k values (max3-fusable chains) + 2 shuffles
    float t0 = fmaxf(fmaxf(fmaxf(s[0][0], s[0][1]), s[0][2]), s[0][3]);
    float t1 = fmaxf(fmaxf(fmaxf(s[1][0], s[1][1]), s[1][2]), s[1][3]);
    float t2 = fmaxf(fmaxf(fmaxf(s[2][0], s[2][1]), s[2][2]), s[2][3]);
    float t3 = fmaxf(fmaxf(fmaxf(s[3][0], s[3][1]), s[3][2]), s[3][3]);
    float pmax = fmaxf(fmaxf(fmaxf(t0, t1), t2), t3);
    pmax = fmaxf(pmax, __shfl_xor(pmax, 16));
    pmax = fmaxf(pmax, __shfl_xor(pmax, 32));
    // defer-rescale (T13): only rescale when max grew by > 8 (log2 units)
    if(__any(pmax > m_r + 8.f)){
      float mnew  = fmaxf(m_r, pmax);
      float alpha = __builtin_amdgcn_exp2f(m_r - mnew);
      m_r = mnew;
      for(int g=0;g<4;g++){
        f32x4 a = accT[g];
        for(int r=0;r<4;r++) a[r] *= alpha;
        accT[g] = a;
      }
      for(int r=0;r<4;r++) accL[r] *= alpha;
    }
    for(int g=0;g<4;g++)
      for(int r=0;r<4;r++)
        s[g][r] = __builtin_amdgcn_exp2f(s[g][r] - m_r);

    // pack P (k-contiguous groups of 4) -> per-wave LDS [q=16][k=64], swizzled
    for(int g=0;g<4;g++){
      bf16x4 pk;
      for(int r=0;r<4;r++) pk[r] = (__bf16)s[g][r];
      int idx = (l15*64 + g*16 + l4*4) ^ ((l15 & 7) << 3);
      *(bf16x4*)(&Psm[w][idx]) = pk;
    }

    // O^T += V^T · P^T ; denominator row via all-ones A-frag
    __builtin_amdgcn_s_setprio(1);
    for(int c=0;c<2;c++){
      int idx_p = (l15*64 + c*32 + l4*8) ^ ((l15 & 7) << 3);
      bf16x8 pf = *(const bf16x8*)(&Psm[w][idx_p]);
      accL = __builtin_amdgcn_mfma_f32_16x16x32_bf16(ones, pf, accL, 0,0,0);
      for(int g=0;g<4;g++){
        int row = g*16 + l15;
        int idx = (row*64 + c*32 + l4*8) ^ ((row & 7) << 3);
        bf16x8 vf = *(const bf16x8*)(&Vsm[cur][idx]);
        accT[g] = __builtin_amdgcn_mfma_f32_16x16x32_bf16(vf, pf, accT[g], 0,0,0);
      }
    }
    __builtin_amdgcn_s_setprio(0);

    __syncthreads();                   // next tile ready; all waves done with cur
  };

  for(int t2=0; t2<16; ++t2){
    body(2*t2,   0);                   // compile-time cur -> hoisted LDS addresses
    body(2*t2+1, 1);
  }

  // normalize + write O^T -> attn [B*T, H*64] bf16 (4 consecutive d per store)
  float oinv = 1.0f / accL[0];         // all rows of the ones-MFMA are identical
  int m = b*T_ + qt*64 + w*16 + l15;
  for(int g=0;g<4;g++){
    bf16x4 pk;
    for(int r=0;r<4;r++) pk[r] = (__bf16)(accT[g][r] * oinv);
    *(bf16x4*)(attn_out + (size_t)m*1024 + h*64 + g*16 + l4*4) = pk;
  }
}

// ---------------- final GEMM: attn[4096,1024] x WoT + bo -> fp32 out ----------------
// 64x128 tile, 512 blocks; C^T accumulation -> float4 stores
__global__ __launch_bounds__(256) void k_gemm_out(const u16* __restrict__ A,
                                                  const u16* __restrict__ BT,
                                                  const float* __restrict__ bias,
                                                  float* __restrict__ out){
  int n0 = blockIdx.x * 128;
  int m0 = blockIdx.y * 64;
  __shared__ u16 Asm[64*64];          // 8 KB
  __shared__ u16 Bsm[128*64];         // 16 KB
  int t = threadIdx.x;
  int lane = t & 63, w = t >> 6, wm = w >> 1, wn = w & 1;
  int l15 = lane & 15, l4 = lane >> 4;
  f32x4 zero = {0.f,0.f,0.f,0.f};
  f32x4 acc[2][4];
  for(int i=0;i<2;i++) for(int j=0;j<4;j++) acc[i][j] = zero;
  int srow = t >> 3, schunk = t & 7;

  for(int kt=0; kt<16; ++kt){
    __syncthreads();
    int kb = kt * 64;
    for(int i=0;i<2;i++){
      int row = i*32 + srow;
      int gch = schunk ^ (row & 7);
      gl_lds16(A  + (size_t)(m0+row)*1024 + kb + gch*8, Asm + row*64 + schunk*8);
    }
    for(int i=0;i<4;i++){
      int row = i*32 + srow;
      int gch = schunk ^ (row & 7);
      gl_lds16(BT + (size_t)(n0+row)*1024 + kb + gch*8, Bsm + row*64 + schunk*8);
    }
    __syncthreads();
    for(int c=0;c<2;c++){
      bf16x8 af[2], bfr[4];
      for(int mt=0;mt<2;mt++){
        int row = wm*32 + mt*16 + l15;
        int idx = (row*64 + c*32 + l4*8) ^ ((row & 7) << 3);
        af[mt] = *(const bf16x8*)(Asm + idx);
      }
      for(int nt=0;nt<4;nt++){
        int row = wn*64 + nt*16 + l15;
        int idx = (row*64 + c*32 + l4*8) ^ ((row & 7) << 3);
        bfr[nt] = *(const bf16x8*)(Bsm + idx);
      }
      for(int mt=0;mt<2;mt++)
        for(int nt=0;nt<4;nt++)
          acc[mt][nt] = __builtin_amdgcn_mfma_f32_16x16x32_bf16(bfr[nt], af[mt], acc[mt][nt], 0,0,0);
    }
  }
  // C^T epilogue: reg-axis = n -> float4 stores
  for(int nt=0;nt<4;nt++){
    int nb = n0 + wn*64 + nt*16 + l4*4;
    float4 b4 = *(const float4*)&bias[nb];
    for(int mt=0;mt<2;mt++){
      int m = m0 + wm*32 + mt*16 + l15;
      float4 o;
      o.x = acc[mt][nt][0] + b4.x;
      o.y = acc[mt][nt][1] + b4.y;
      o.z = acc[mt][nt][2] + b4.z;
      o.w = acc[mt][nt][3] + b4.w;
      *(float4*)&out[(size_t)m*1024 + nb] = o;
    }
  }
}

extern "C" void kernel_launch(void* const* d_in, const int* in_sizes, int n_in,
                              void* d_out, int out_size, void* d_ws, size_t ws_size,
                              hipStream_t stream){
  const float* x  = (const float*)d_in[0];
  const float* Wq = (const float*)d_in[1];
  const float* bq = (const float*)d_in[2];
  const float* Wk = (const float*)d_in[3];
  const float* bk = (const float*)d_in[4];
  const float* Wv = (const float*)d_in[5];
  const float* bv = (const float*)d_in[6];
  const float* Wo = (const float*)d_in[7];
  const float* bo = (const float*)d_in[8];
  float* out = (float*)d_out;
  char* ws = (char*)d_ws;

  u16* xb  = (u16*)(ws);                    // 8 MB  : x bf16 [4096,1024]
  u16* wt  = (u16*)(ws + (8u  << 20));      // 8 MB  : WqT,WkT,WvT,WoT bf16 [1024,1024] each
  u16* qkv = (u16*)(ws + (16u << 20));      // 16 MB : Q,K bf16 [BH,T,64] each
  u16* vt  = (u16*)(ws + (40u << 20));      // 8 MB  : VT bf16 [BH,64,T] (written by qkv GEMM)
  u16* at  = (u16*)(ws + (48u << 20));      // 8 MB  : attn bf16 [4096,1024]

  k_cvt_x   <<<4096, 256, 0, stream>>>(x, xb);
  k_tconv_w <<<dim3(32,32,4), dim3(32,8), 0, stream>>>(Wq, Wk, Wv, Wo, wt);
  k_gemm_qkv<<<dim3(24,32), 256, 0, stream>>>(xb, wt, bq, bk, bv, qkv, vt);
  k_attn    <<<1024, 256, 0, stream>>>(qkv, qkv + (size_t)4*1024*1024, vt, at);
  k_gemm_out<<<dim3(8,64), 256, 0, stream>>>(at, wt + (size_t)3*1024*1024, bo, out);
}

// Round 8
// 206.529 us; speedup vs baseline: 1.0765x; 1.0765x over previous
//
#include <hip/hip_runtime.h>
#include <hip/hip_bf16.h>
#include <stdint.h>

#define B_  2
#define T_  2048
#define D_  1024
#define H_  16
#define KS  64
#define M_  (B_*T_)    // 4096

typedef unsigned short u16;
typedef __bf16 bf16x8 __attribute__((ext_vector_type(8)));
typedef __bf16 bf16x4 __attribute__((ext_vector_type(4)));
typedef float  f32x4  __attribute__((ext_vector_type(4)));

#define AS1 __attribute__((address_space(1)))
#define AS3 __attribute__((address_space(3)))

__device__ inline u16 f2bf(float x){
  union { float f; uint32_t u; } v; v.f = x;
  uint32_t r = (v.u + 0x7fffu + ((v.u >> 16) & 1u)) >> 16;
  return (u16)r;
}

__device__ inline void gl_lds16(const u16* g, u16* l){
  __builtin_amdgcn_global_load_lds((AS1 void*)(const_cast<u16*>(g)),
                                   (AS3 void*)l, 16, 0, 0);
}

// ---------------- x fp32 -> bf16 ----------------
__global__ __launch_bounds__(256) void k_cvt_x(const float* __restrict__ x,
                                               u16* __restrict__ xb){
  int i = blockIdx.x * 256 + threadIdx.x;
  float4 v = ((const float4*)x)[i];
  ushort4 o;
  o.x = f2bf(v.x); o.y = f2bf(v.y); o.z = f2bf(v.z); o.w = f2bf(v.w);
  ((ushort4*)xb)[i] = o;
}

// ---------------- W [K,N] fp32 -> WT [N,K] bf16 (all 4 weights) ----------------
__global__ __launch_bounds__(256) void k_tconv_w(const float* __restrict__ W0,
                                                 const float* __restrict__ W1,
                                                 const float* __restrict__ W2,
                                                 const float* __restrict__ W3,
                                                 u16* __restrict__ out){
  const float* W = (blockIdx.z==0)?W0:(blockIdx.z==1)?W1:(blockIdx.z==2)?W2:W3;
  u16* o = out + (size_t)blockIdx.z * 1024 * 1024;
  __shared__ float tile[32][33];
  int tx = threadIdx.x, ty = threadIdx.y;          // 32 x 8
  int kb = blockIdx.y * 32, nb = blockIdx.x * 32;
  for(int i=0;i<4;i++) tile[ty+8*i][tx] = W[(size_t)(kb+ty+8*i)*1024 + nb+tx];
  __syncthreads();
  for(int i=0;i<4;i++){
    int n = nb + ty + 8*i;
    o[(size_t)n*1024 + kb + tx] = f2bf(tile[tx][ty+8*i]);
  }
}

// ---------------- QKV GEMM core (branch-free inner loop, template-unswitched) ----------------
// CT=true : acc = C^T (reg-axis = n), for Q/K packed stores
// CT=false: acc = C   (reg-axis = m), for V-transposed stores
template<bool CT>
__device__ inline void qkv_core(const u16* __restrict__ xb, const u16* __restrict__ BT,
                                int m0, int n0, u16* Asm, u16* Bsm,
                                f32x4 (&acc)[4][4],
                                int lane, int wm, int wn){
  int l15 = lane & 15, l4 = lane >> 4;
  int t = wm*128 + wn*64 + lane;  // not used; placeholder
  (void)t;
  int tid = threadIdx.x;
  int srow = tid >> 3, schunk = tid & 7;
  for(int kt=0; kt<16; ++kt){
    __syncthreads();
    int kb = kt * 64;
    for(int i=0;i<4;i++){
      int row = i*32 + srow;
      int gch = schunk ^ (row & 7);           // pre-swizzled global source (T2)
      gl_lds16(xb + (size_t)(m0+row)*1024 + kb + gch*8, Asm + row*64 + schunk*8);
      gl_lds16(BT + (size_t)(n0+row)*1024 + kb + gch*8, Bsm + row*64 + schunk*8);
    }
    __syncthreads();
    for(int c=0;c<2;c++){
      bf16x8 af[4], bfr[4];
      for(int mt=0;mt<4;mt++){
        int row = wm*64 + mt*16 + l15;
        int idx = (row*64 + c*32 + l4*8) ^ ((row & 7) << 3);
        af[mt] = *(const bf16x8*)(Asm + idx);
      }
      for(int nt=0;nt<4;nt++){
        int row = wn*64 + nt*16 + l15;
        int idx = (row*64 + c*32 + l4*8) ^ ((row & 7) << 3);
        bfr[nt] = *(const bf16x8*)(Bsm + idx);
      }
      for(int mt=0;mt<4;mt++)
        for(int nt=0;nt<4;nt++){
          if(CT)
            acc[mt][nt] = __builtin_amdgcn_mfma_f32_16x16x32_bf16(bfr[nt], af[mt], acc[mt][nt], 0,0,0);
          else
            acc[mt][nt] = __builtin_amdgcn_mfma_f32_16x16x32_bf16(af[mt], bfr[nt], acc[mt][nt], 0,0,0);
        }
    }
  }
}

// Q,K computed as C^T (reg-axis = kk) -> packed bf16x4 stores to [B,H,T,64];
// V computed normal (reg-axis = t)   -> packed bf16x4 stores to VT [B*H,64,T].
// Q pre-scaled by (1/8)*log2(e) for exp2 softmax.
__global__ __launch_bounds__(256) void k_gemm_qkv(const u16* __restrict__ xb,
                                                  const u16* __restrict__ wt,
                                                  const float* __restrict__ bq,
                                                  const float* __restrict__ bk,
                                                  const float* __restrict__ bv,
                                                  u16* __restrict__ qkv,
                                                  u16* __restrict__ vt){
  int widx = blockIdx.x >> 3;                 // 0..2 : q,k,v
  int n0   = (blockIdx.x & 7) * 128;
  int m0   = blockIdx.y * 128;
  const u16* BT = wt + (size_t)widx * (1024*1024);
  const float* bias = (widx==0)?bq:(widx==1)?bk:bv;
  u16* out = qkv + (size_t)widx * (4*1024*1024);
  float oscale = (widx==0) ? 0.125f * 1.44269504088896f : 1.0f;

  __shared__ u16 Asm[128*64];
  __shared__ u16 Bsm[128*64];
  int t = threadIdx.x;
  int lane = t & 63, w = t >> 6, wm = w >> 1, wn = w & 1;
  int l15 = lane & 15, l4 = lane >> 4;
  f32x4 zero = {0.f,0.f,0.f,0.f};
  f32x4 acc[4][4];
  for(int i=0;i<4;i++) for(int j=0;j<4;j++) acc[i][j] = zero;

  if(widx < 2){
    qkv_core<true >(xb, BT, m0, n0, Asm, Bsm, acc, lane, wm, wn);
    // Q/K epilogue (C^T): 4 consecutive kk per lane -> packed bf16x4 to [B,H,T,64]
    for(int nt=0;nt<4;nt++){
      int nb = n0 + wn*64 + nt*16 + l4*4;
      float4 b4 = *(const float4*)&bias[nb];
      int h = nb >> 6, kk = nb & 63;
      for(int mt=0;mt<4;mt++){
        int m = m0 + wm*64 + mt*16 + l15;
        int b = m >> 11, tt = m & 2047;
        bf16x4 pk;
        pk[0] = (__bf16)((acc[mt][nt][0] + b4.x) * oscale);
        pk[1] = (__bf16)((acc[mt][nt][1] + b4.y) * oscale);
        pk[2] = (__bf16)((acc[mt][nt][2] + b4.z) * oscale);
        pk[3] = (__bf16)((acc[mt][nt][3] + b4.w) * oscale);
        *(bf16x4*)(out + (((size_t)(b*H_ + h)*T_ + tt) << 6) + kk) = pk;
      }
    }
  } else {
    qkv_core<false>(xb, BT, m0, n0, Asm, Bsm, acc, lane, wm, wn);
    // V epilogue: write transposed directly -> VT [B*H, 64, T], packed 4-t stores
    for(int nt=0;nt<4;nt++){
      int nbase = n0 + wn*64 + nt*16 + l15;
      float bv_ = bias[nbase];
      int h = nbase >> 6, kk = nbase & 63;
      for(int mt=0;mt<4;mt++){
        int m = m0 + wm*64 + mt*16 + l4*4;    // 4 consecutive t
        int b = m >> 11, tt = m & 2047;
        bf16x4 pk;
        for(int r=0;r<4;r++) pk[r] = (__bf16)(acc[mt][nt][r] + bv_);
        *(bf16x4*)(vt + (((size_t)(b*H_ + h)*64 + kk)*T_) + tt) = pk;
      }
    }
  }
}

// ---------------- flash attention (swapped-QK, O^T; ones-trick; XCD swizzle T1) ----------------
__global__ __launch_bounds__(256, 3) void k_attn(const u16* __restrict__ Q,
                                                 const u16* __restrict__ Kg,
                                                 const u16* __restrict__ VT,
                                                 u16* __restrict__ attn_out){
  // XCD-aware swizzle (bijective, 1024 = 8 XCD x 128): all 32 q-blocks of one
  // (b,h) land on one XCD -> its K/V (512 KB) stays in that XCD's L2.
  int bx0 = blockIdx.x;
  int bx  = (bx0 & 7) * 128 + (bx0 >> 3);
  int qt = bx & 31, h = (bx >> 5) & 15, b = bx >> 9;
  int bh = b*H_ + h;
  const u16* Qh = Q  + (size_t)bh * T_ * 64;
  const u16* Kh = Kg + (size_t)bh * T_ * 64;
  const u16* Vh = VT + (size_t)bh * 64 * T_;
  __shared__ u16 Ksm[2][64*64];
  __shared__ u16 Vsm[2][64*64];
  __shared__ u16 Psm[4][16*64];
  int t = threadIdx.x, lane = t & 63, w = t >> 6;
  int l15 = lane & 15, l4 = lane >> 4;

  // Q fragments (B operand; cols q = l15), held all kernel
  bf16x8 qf[2];
  int qrow = qt*64 + w*16 + l15;
  for(int c=0;c<2;c++)
    qf[c] = *(const bf16x8*)(Qh + (size_t)qrow*64 + c*32 + l4*8);

  bf16x8 ones;
  for(int j=0;j<8;j++) ones[j] = (__bf16)1.0f;

  f32x4 zero = {0.f,0.f,0.f,0.f};
  f32x4 accT[4];                       // O^T: row d = g*16+l4*4+r, col q = l15
  for(int g=0;g<4;g++) accT[g] = zero;
  f32x4 accL = zero;                   // softmax denominator (ones-row MFMA)
  float m_r = -3.0e38f;                // per-lane running max for q = l15

  int srow = t >> 3, schunk = t & 7;
  int gchS = schunk ^ (srow & 7);      // staging swizzle chunk

  // prologue: stage tile 0
  gl_lds16(Kh + (size_t)srow*64      + gchS*8, &Ksm[0][srow*64      + schunk*8]);
  gl_lds16(Kh + (size_t)(srow+32)*64 + gchS*8, &Ksm[0][(srow+32)*64 + schunk*8]);
  gl_lds16(Vh + (size_t)srow*T_      + gchS*8, &Vsm[0][srow*64      + schunk*8]);
  gl_lds16(Vh + (size_t)(srow+32)*T_ + gchS*8, &Vsm[0][(srow+32)*64 + schunk*8]);
  __syncthreads();

  auto body = [&](int tile, int cur){
    // issue next tile into the other buffer (hidden under compute)
    if(tile+1 < 32){
      int kvb = (tile+1)*64;
      gl_lds16(Kh + (size_t)(kvb+srow)*64    + gchS*8, &Ksm[cur^1][srow*64      + schunk*8]);
      gl_lds16(Kh + (size_t)(kvb+srow+32)*64 + gchS*8, &Ksm[cur^1][(srow+32)*64 + schunk*8]);
      gl_lds16(Vh + (size_t)srow*T_      + kvb + gchS*8, &Vsm[cur^1][srow*64      + schunk*8]);
      gl_lds16(Vh + (size_t)(srow+32)*T_ + kvb + gchS*8, &Vsm[cur^1][(srow+32)*64 + schunk*8]);
    }

    // S^T = K · Q^T : s[g] row = k = g*16 + l4*4 + r, col = q = l15
    f32x4 s[4];
    for(int g=0;g<4;g++) s[g] = zero;
    __builtin_amdgcn_s_setprio(1);
    for(int c=0;c<2;c++){
      for(int g=0;g<4;g++){
        int row = g*16 + l15;
        int idx = (row*64 + c*32 + l4*8) ^ ((row & 7) << 3);
        bf16x8 kf = *(const bf16x8*)(&Ksm[cur][idx]);
        s[g] = __builtin_amdgcn_mfma_f32_16x16x32_bf16(kf, qf[c], s[g], 0,0,0);
      }
    }
    __builtin_amdgcn_s_setprio(0);

    // per-lane max over 16 in-register k values + 2 shuffles
    float t0 = fmaxf(fmaxf(fmaxf(s[0][0], s[0][1]), s[0][2]), s[0][3]);
    float t1 = fmaxf(fmaxf(fmaxf(s[1][0], s[1][1]), s[1][2]), s[1][3]);
    float t2 = fmaxf(fmaxf(fmaxf(s[2][0], s[2][1]), s[2][2]), s[2][3]);
    float t3 = fmaxf(fmaxf(fmaxf(s[3][0], s[3][1]), s[3][2]), s[3][3]);
    float pmax = fmaxf(fmaxf(fmaxf(t0, t1), t2), t3);
    pmax = fmaxf(pmax, __shfl_xor(pmax, 16));
    pmax = fmaxf(pmax, __shfl_xor(pmax, 32));
    // defer-rescale (T13)
    if(__any(pmax > m_r + 8.f)){
      float mnew  = fmaxf(m_r, pmax);
      float alpha = __builtin_amdgcn_exp2f(m_r - mnew);
      m_r = mnew;
      for(int g=0;g<4;g++){
        f32x4 a = accT[g];
        for(int r=0;r<4;r++) a[r] *= alpha;
        accT[g] = a;
      }
      for(int r=0;r<4;r++) accL[r] *= alpha;
    }
    for(int g=0;g<4;g++)
      for(int r=0;r<4;r++)
        s[g][r] = __builtin_amdgcn_exp2f(s[g][r] - m_r);

    // pack P -> per-wave LDS [q=16][k=64], swizzled
    for(int g=0;g<4;g++){
      bf16x4 pk;
      for(int r=0;r<4;r++) pk[r] = (__bf16)s[g][r];
      int idx = (l15*64 + g*16 + l4*4) ^ ((l15 & 7) << 3);
      *(bf16x4*)(&Psm[w][idx]) = pk;
    }

    // O^T += V^T · P^T ; denominator row via all-ones A-frag
    __builtin_amdgcn_s_setprio(1);
    for(int c=0;c<2;c++){
      int idx_p = (l15*64 + c*32 + l4*8) ^ ((l15 & 7) << 3);
      bf16x8 pf = *(const bf16x8*)(&Psm[w][idx_p]);
      accL = __builtin_amdgcn_mfma_f32_16x16x32_bf16(ones, pf, accL, 0,0,0);
      for(int g=0;g<4;g++){
        int row = g*16 + l15;
        int idx = (row*64 + c*32 + l4*8) ^ ((row & 7) << 3);
        bf16x8 vf = *(const bf16x8*)(&Vsm[cur][idx]);
        accT[g] = __builtin_amdgcn_mfma_f32_16x16x32_bf16(vf, pf, accT[g], 0,0,0);
      }
    }
    __builtin_amdgcn_s_setprio(0);

    __syncthreads();
  };

  for(int t2=0; t2<16; ++t2){
    body(2*t2,   0);                   // compile-time cur -> hoisted LDS addresses
    body(2*t2+1, 1);
  }

  // normalize + write O^T -> attn [B*T, H*64] bf16
  float oinv = 1.0f / accL[0];
  int m = b*T_ + qt*64 + w*16 + l15;
  for(int g=0;g<4;g++){
    bf16x4 pk;
    for(int r=0;r<4;r++) pk[r] = (__bf16)(accT[g][r] * oinv);
    *(bf16x4*)(attn_out + (size_t)m*1024 + h*64 + g*16 + l4*4) = pk;
  }
}

// ---------------- final GEMM: attn[4096,1024] x WoT + bo -> fp32 out ----------------
// 64x128 tile, 512 blocks; C^T accumulation -> float4 stores
__global__ __launch_bounds__(256) void k_gemm_out(const u16* __restrict__ A,
                                                  const u16* __restrict__ BT,
                                                  const float* __restrict__ bias,
                                                  float* __restrict__ out){
  int n0 = blockIdx.x * 128;
  int m0 = blockIdx.y * 64;
  __shared__ u16 Asm[64*64];          // 8 KB
  __shared__ u16 Bsm[128*64];         // 16 KB
  int t = threadIdx.x;
  int lane = t & 63, w = t >> 6, wm = w >> 1, wn = w & 1;
  int l15 = lane & 15, l4 = lane >> 4;
  f32x4 zero = {0.f,0.f,0.f,0.f};
  f32x4 acc[2][4];
  for(int i=0;i<2;i++) for(int j=0;j<4;j++) acc[i][j] = zero;
  int srow = t >> 3, schunk = t & 7;

  for(int kt=0; kt<16; ++kt){
    __syncthreads();
    int kb = kt * 64;
    for(int i=0;i<2;i++){
      int row = i*32 + srow;
      int gch = schunk ^ (row & 7);
      gl_lds16(A  + (size_t)(m0+row)*1024 + kb + gch*8, Asm + row*64 + schunk*8);
    }
    for(int i=0;i<4;i++){
      int row = i*32 + srow;
      int gch = schunk ^ (row & 7);
      gl_lds16(BT + (size_t)(n0+row)*1024 + kb + gch*8, Bsm + row*64 + schunk*8);
    }
    __syncthreads();
    for(int c=0;c<2;c++){
      bf16x8 af[2], bfr[4];
      for(int mt=0;mt<2;mt++){
        int row = wm*32 + mt*16 + l15;
        int idx = (row*64 + c*32 + l4*8) ^ ((row & 7) << 3);
        af[mt] = *(const bf16x8*)(Asm + idx);
      }
      for(int nt=0;nt<4;nt++){
        int row = wn*64 + nt*16 + l15;
        int idx = (row*64 + c*32 + l4*8) ^ ((row & 7) << 3);
        bfr[nt] = *(const bf16x8*)(Bsm + idx);
      }
      for(int mt=0;mt<2;mt++)
        for(int nt=0;nt<4;nt++)
          acc[mt][nt] = __builtin_amdgcn_mfma_f32_16x16x32_bf16(bfr[nt], af[mt], acc[mt][nt], 0,0,0);
    }
  }
  // C^T epilogue: reg-axis = n -> float4 stores
  for(int nt=0;nt<4;nt++){
    int nb = n0 + wn*64 + nt*16 + l4*4;
    float4 b4 = *(const float4*)&bias[nb];
    for(int mt=0;mt<2;mt++){
      int m = m0 + wm*32 + mt*16 + l15;
      float4 o;
      o.x = acc[mt][nt][0] + b4.x;
      o.y = acc[mt][nt][1] + b4.y;
      o.z = acc[mt][nt][2] + b4.z;
      o.w = acc[mt][nt][3] + b4.w;
      *(float4*)&out[(size_t)m*1024 + nb] = o;
    }
  }
}

extern "C" void kernel_launch(void* const* d_in, const int* in_sizes, int n_in,
                              void* d_out, int out_size, void* d_ws, size_t ws_size,
                              hipStream_t stream){
  const float* x  = (const float*)d_in[0];
  const float* Wq = (const float*)d_in[1];
  const float* bq = (const float*)d_in[2];
  const float* Wk = (const float*)d_in[3];
  const float* bk = (const float*)d_in[4];
  const float* Wv = (const float*)d_in[5];
  const float* bv = (const float*)d_in[6];
  const float* Wo = (const float*)d_in[7];
  const float* bo = (const float*)d_in[8];
  float* out = (float*)d_out;
  char* ws = (char*)d_ws;

  u16* xb  = (u16*)(ws);                    // 8 MB  : x bf16 [4096,1024]
  u16* wt  = (u16*)(ws + (8u  << 20));      // 8 MB  : WqT,WkT,WvT,WoT bf16 [1024,1024] each
  u16* qkv = (u16*)(ws + (16u << 20));      // 16 MB : Q,K bf16 [BH,T,64] each
  u16* vt  = (u16*)(ws + (40u << 20));      // 8 MB  : VT bf16 [BH,64,T] (written by qkv GEMM)
  u16* at  = (u16*)(ws + (48u << 20));      // 8 MB  : attn bf16 [4096,1024]

  k_cvt_x   <<<4096, 256, 0, stream>>>(x, xb);
  k_tconv_w <<<dim3(32,32,4), dim3(32,8), 0, stream>>>(Wq, Wk, Wv, Wo, wt);
  k_gemm_qkv<<<dim3(24,32), 256, 0, stream>>>(xb, wt, bq, bk, bv, qkv, vt);
  k_attn    <<<1024, 256, 0, stream>>>(qkv, qkv + (size_t)4*1024*1024, vt, at);
  k_gemm_out<<<dim3(8,64), 256, 0, stream>>>(at, wt + (size_t)3*1024*1024, bo, out);
}

// Round 9
// 201.117 us; speedup vs baseline: 1.1055x; 1.0269x over previous
//
#include <hip/hip_runtime.h>
#include <hip/hip_bf16.h>
#include <stdint.h>

#define B_  2
#define T_  2048
#define D_  1024
#define H_  16
#define KS  64
#define M_  (B_*T_)    // 4096

typedef unsigned short u16;
typedef __bf16 bf16x8 __attribute__((ext_vector_type(8)));
typedef __bf16 bf16x4 __attribute__((ext_vector_type(4)));
typedef float  f32x4  __attribute__((ext_vector_type(4)));

#define AS1 __attribute__((address_space(1)))
#define AS3 __attribute__((address_space(3)))

__device__ inline u16 f2bf(float x){
  union { float f; uint32_t u; } v; v.f = x;
  uint32_t r = (v.u + 0x7fffu + ((v.u >> 16) & 1u)) >> 16;
  return (u16)r;
}

__device__ inline void gl_lds16(const u16* g, u16* l){
  __builtin_amdgcn_global_load_lds((AS1 void*)(const_cast<u16*>(g)),
                                   (AS3 void*)l, 16, 0, 0);
}

// ---------------- fused prep: x fp32->bf16  +  W transpose-convert ----------------
__global__ __launch_bounds__(256) void k_prep(const float* __restrict__ x,
                                              u16* __restrict__ xb,
                                              const float* __restrict__ W0,
                                              const float* __restrict__ W1,
                                              const float* __restrict__ W2,
                                              const float* __restrict__ W3,
                                              u16* __restrict__ wt){
  int bid = blockIdx.x, tid = threadIdx.x;
  if(bid < 4096){
    int i = bid * 256 + tid;
    float4 v = ((const float4*)x)[i];
    ushort4 o;
    o.x = f2bf(v.x); o.y = f2bf(v.y); o.z = f2bf(v.z); o.w = f2bf(v.w);
    ((ushort4*)xb)[i] = o;
  } else {
    int pid = bid - 4096;
    int z = pid >> 10, rem = pid & 1023;
    int by = rem >> 5, bx = rem & 31;
    const float* W = (z==0)?W0:(z==1)?W1:(z==2)?W2:W3;
    u16* o = wt + (size_t)z * 1024 * 1024;
    __shared__ float tile[32][33];
    int tx = tid & 31, ty = tid >> 5;               // 32 x 8
    int kb = by * 32, nb = bx * 32;
    for(int i=0;i<4;i++) tile[ty+8*i][tx] = W[(size_t)(kb+ty+8*i)*1024 + nb+tx];
    __syncthreads();
    for(int i=0;i<4;i++){
      int n = nb + ty + 8*i;
      o[(size_t)n*1024 + kb + tx] = f2bf(tile[tx][ty+8*i]);
    }
  }
}

// ---------------- QKV GEMM core (branch-free inner loop, template-unswitched) ----------------
template<bool CT>
__device__ inline void qkv_core(const u16* __restrict__ xb, const u16* __restrict__ BT,
                                int m0, int n0, u16* Asm, u16* Bsm,
                                f32x4 (&acc)[4][4],
                                int lane, int wm, int wn){
  int l15 = lane & 15, l4 = lane >> 4;
  int tid = threadIdx.x;
  int srow = tid >> 3, schunk = tid & 7;
  for(int kt=0; kt<16; ++kt){
    __syncthreads();
    int kb = kt * 64;
    for(int i=0;i<4;i++){
      int row = i*32 + srow;
      int gch = schunk ^ (row & 7);           // pre-swizzled global source (T2)
      gl_lds16(xb + (size_t)(m0+row)*1024 + kb + gch*8, Asm + row*64 + schunk*8);
      gl_lds16(BT + (size_t)(n0+row)*1024 + kb + gch*8, Bsm + row*64 + schunk*8);
    }
    __syncthreads();
    for(int c=0;c<2;c++){
      bf16x8 af[4], bfr[4];
      for(int mt=0;mt<4;mt++){
        int row = wm*64 + mt*16 + l15;
        int idx = (row*64 + c*32 + l4*8) ^ ((row & 7) << 3);
        af[mt] = *(const bf16x8*)(Asm + idx);
      }
      for(int nt=0;nt<4;nt++){
        int row = wn*64 + nt*16 + l15;
        int idx = (row*64 + c*32 + l4*8) ^ ((row & 7) << 3);
        bfr[nt] = *(const bf16x8*)(Bsm + idx);
      }
      for(int mt=0;mt<4;mt++)
        for(int nt=0;nt<4;nt++){
          if(CT)
            acc[mt][nt] = __builtin_amdgcn_mfma_f32_16x16x32_bf16(bfr[nt], af[mt], acc[mt][nt], 0,0,0);
          else
            acc[mt][nt] = __builtin_amdgcn_mfma_f32_16x16x32_bf16(af[mt], bfr[nt], acc[mt][nt], 0,0,0);
        }
    }
  }
}

// Q,K as C^T -> packed bf16x4 stores to [B,H,T,64]; V normal -> VT [B*H,64,T].
// Q pre-scaled by (1/8)*log2(e). 1D grid 768 with XCD swizzle: each XCD owns a
// 4-m-tile stripe (A-panel L2 locality; B panels are L3-resident).
__global__ __launch_bounds__(256) void k_gemm_qkv(const u16* __restrict__ xb,
                                                  const u16* __restrict__ wt,
                                                  const float* __restrict__ bq,
                                                  const float* __restrict__ bk,
                                                  const float* __restrict__ bv,
                                                  u16* __restrict__ qkv,
                                                  u16* __restrict__ vt){
  int bid = blockIdx.x;
  int sw  = (bid & 7) * 96 + (bid >> 3);      // 768 = 8 XCD x 96, bijective
  int mt_ = sw / 24, r = sw % 24;
  int widx = r >> 3;                          // 0..2 : q,k,v
  int n0   = (r & 7) * 128;
  int m0   = mt_ * 128;
  const u16* BT = wt + (size_t)widx * (1024*1024);
  const float* bias = (widx==0)?bq:(widx==1)?bk:bv;
  u16* out = qkv + (size_t)widx * (4*1024*1024);
  float oscale = (widx==0) ? 0.125f * 1.44269504088896f : 1.0f;

  __shared__ u16 Asm[128*64];
  __shared__ u16 Bsm[128*64];
  int t = threadIdx.x;
  int lane = t & 63, w = t >> 6, wm = w >> 1, wn = w & 1;
  int l15 = lane & 15, l4 = lane >> 4;
  f32x4 zero = {0.f,0.f,0.f,0.f};
  f32x4 acc[4][4];
  for(int i=0;i<4;i++) for(int j=0;j<4;j++) acc[i][j] = zero;

  if(widx < 2){
    qkv_core<true >(xb, BT, m0, n0, Asm, Bsm, acc, lane, wm, wn);
    for(int nt=0;nt<4;nt++){
      int nb = n0 + wn*64 + nt*16 + l4*4;
      float4 b4 = *(const float4*)&bias[nb];
      int h = nb >> 6, kk = nb & 63;
      for(int mt=0;mt<4;mt++){
        int m = m0 + wm*64 + mt*16 + l15;
        int b = m >> 11, tt = m & 2047;
        bf16x4 pk;
        pk[0] = (__bf16)((acc[mt][nt][0] + b4.x) * oscale);
        pk[1] = (__bf16)((acc[mt][nt][1] + b4.y) * oscale);
        pk[2] = (__bf16)((acc[mt][nt][2] + b4.z) * oscale);
        pk[3] = (__bf16)((acc[mt][nt][3] + b4.w) * oscale);
        *(bf16x4*)(out + (((size_t)(b*H_ + h)*T_ + tt) << 6) + kk) = pk;
      }
    }
  } else {
    qkv_core<false>(xb, BT, m0, n0, Asm, Bsm, acc, lane, wm, wn);
    for(int nt=0;nt<4;nt++){
      int nbase = n0 + wn*64 + nt*16 + l15;
      float bv_ = bias[nbase];
      int h = nbase >> 6, kk = nbase & 63;
      for(int mt=0;mt<4;mt++){
        int m = m0 + wm*64 + mt*16 + l4*4;    // 4 consecutive t
        int b = m >> 11, tt = m & 2047;
        bf16x4 pk;
        for(int r2=0;r2<4;r2++) pk[r2] = (__bf16)(acc[mt][nt][r2] + bv_);
        *(bf16x4*)(vt + (((size_t)(b*H_ + h)*64 + kk)*T_) + tt) = pk;
      }
    }
  }
}

// ---------------- flash attention: 32 q per wave (2 q-sets share K/V frags) ----------------
// LDS-BW was the bound (r8 audit: ~70% LDS-pipe busy; K/V frags identical across
// waves). Two q-sets per wave halve per-q LDS reads. Block = 128 q, grid 512.
__global__ __launch_bounds__(256, 2) void k_attn(const u16* __restrict__ Q,
                                                 const u16* __restrict__ Kg,
                                                 const u16* __restrict__ VT,
                                                 u16* __restrict__ attn_out){
  // XCD swizzle (512 = 8 x 64): each XCD owns 4 (b,h) groups -> K/V L2-local
  int bx0 = blockIdx.x;
  int bx  = (bx0 & 7) * 64 + (bx0 >> 3);
  int qt = bx & 15, h = (bx >> 4) & 15, b = bx >> 8;
  int bh = b*H_ + h;
  const u16* Qh = Q  + (size_t)bh * T_ * 64;
  const u16* Kh = Kg + (size_t)bh * T_ * 64;
  const u16* Vh = VT + (size_t)bh * 64 * T_;
  __shared__ u16 Ksm[2][64*64];        // 16 KB
  __shared__ u16 Vsm[2][64*64];        // 16 KB
  __shared__ u16 Psm[4][32*64];        // 16 KB (per-wave 32 q x 64 k)
  int t = threadIdx.x, lane = t & 63, w = t >> 6;
  int l15 = lane & 15, l4 = lane >> 4;

  // Q fragments: 2 sets x 2 chunks (cols q = l15 / l15+16)
  bf16x8 qf[2][2];
  for(int ss=0; ss<2; ++ss){
    int qrow = qt*128 + w*32 + ss*16 + l15;
    for(int c=0;c<2;c++)
      qf[ss][c] = *(const bf16x8*)(Qh + (size_t)qrow*64 + c*32 + l4*8);
  }

  bf16x8 ones;
  for(int j=0;j<8;j++) ones[j] = (__bf16)1.0f;

  f32x4 zero = {0.f,0.f,0.f,0.f};
  f32x4 accT[2][4];
  for(int ss=0;ss<2;ss++) for(int g=0;g<4;g++) accT[ss][g] = zero;
  f32x4 accL[2] = {zero, zero};
  float m_r[2] = {-3.0e38f, -3.0e38f};

  int srow = t >> 3, schunk = t & 7;
  int gchS = schunk ^ (srow & 7);

  // prologue: stage tile 0
  gl_lds16(Kh + (size_t)srow*64      + gchS*8, &Ksm[0][srow*64      + schunk*8]);
  gl_lds16(Kh + (size_t)(srow+32)*64 + gchS*8, &Ksm[0][(srow+32)*64 + schunk*8]);
  gl_lds16(Vh + (size_t)srow*T_      + gchS*8, &Vsm[0][srow*64      + schunk*8]);
  gl_lds16(Vh + (size_t)(srow+32)*T_ + gchS*8, &Vsm[0][(srow+32)*64 + schunk*8]);
  __syncthreads();

  auto body = [&](int tile, int cur){
    if(tile+1 < 32){
      int kvb = (tile+1)*64;
      gl_lds16(Kh + (size_t)(kvb+srow)*64    + gchS*8, &Ksm[cur^1][srow*64      + schunk*8]);
      gl_lds16(Kh + (size_t)(kvb+srow+32)*64 + gchS*8, &Ksm[cur^1][(srow+32)*64 + schunk*8]);
      gl_lds16(Vh + (size_t)srow*T_      + kvb + gchS*8, &Vsm[cur^1][srow*64      + schunk*8]);
      gl_lds16(Vh + (size_t)(srow+32)*T_ + kvb + gchS*8, &Vsm[cur^1][(srow+32)*64 + schunk*8]);
    }

    // S^T = K · Q^T for both q-sets; K frags read ONCE, used twice
    f32x4 s_[2][4];
    for(int ss=0;ss<2;ss++) for(int g=0;g<4;g++) s_[ss][g] = zero;
    __builtin_amdgcn_s_setprio(1);
    for(int c=0;c<2;c++){
      for(int g=0;g<4;g++){
        int row = g*16 + l15;
        int idx = (row*64 + c*32 + l4*8) ^ ((row & 7) << 3);
        bf16x8 kf = *(const bf16x8*)(&Ksm[cur][idx]);
        s_[0][g] = __builtin_amdgcn_mfma_f32_16x16x32_bf16(kf, qf[0][c], s_[0][g], 0,0,0);
        s_[1][g] = __builtin_amdgcn_mfma_f32_16x16x32_bf16(kf, qf[1][c], s_[1][g], 0,0,0);
      }
    }
    __builtin_amdgcn_s_setprio(0);

    // per-lane softmax over 16 k values per set (+2 shuffles each)
    float pmax[2];
    #pragma unroll
    for(int ss=0;ss<2;ss++){
      float t0 = fmaxf(fmaxf(fmaxf(s_[ss][0][0], s_[ss][0][1]), s_[ss][0][2]), s_[ss][0][3]);
      float t1 = fmaxf(fmaxf(fmaxf(s_[ss][1][0], s_[ss][1][1]), s_[ss][1][2]), s_[ss][1][3]);
      float t2 = fmaxf(fmaxf(fmaxf(s_[ss][2][0], s_[ss][2][1]), s_[ss][2][2]), s_[ss][2][3]);
      float t3 = fmaxf(fmaxf(fmaxf(s_[ss][3][0], s_[ss][3][1]), s_[ss][3][2]), s_[ss][3][3]);
      float p = fmaxf(fmaxf(fmaxf(t0, t1), t2), t3);
      p = fmaxf(p, __shfl_xor(p, 16));
      p = fmaxf(p, __shfl_xor(p, 32));
      pmax[ss] = p;
    }
    // merged defer-rescale gate (T13): one branch for both sets
    if(__any(fmaxf(pmax[0] - m_r[0], pmax[1] - m_r[1]) > 8.f)){
      #pragma unroll
      for(int ss=0;ss<2;ss++){
        float mnew  = fmaxf(m_r[ss], pmax[ss]);
        float alpha = __builtin_amdgcn_exp2f(m_r[ss] - mnew);
        m_r[ss] = mnew;
        for(int g=0;g<4;g++){
          f32x4 a = accT[ss][g];
          for(int r=0;r<4;r++) a[r] *= alpha;
          accT[ss][g] = a;
        }
        for(int r=0;r<4;r++) accL[ss][r] *= alpha;
      }
    }
    #pragma unroll
    for(int ss=0;ss<2;ss++)
      for(int g=0;g<4;g++)
        for(int r=0;r<4;r++)
          s_[ss][g][r] = __builtin_amdgcn_exp2f(s_[ss][g][r] - m_r[ss]);

    // pack P -> per-wave LDS [q=32][k=64], swizzled (row&7 invariant to +16)
    #pragma unroll
    for(int ss=0;ss<2;ss++){
      int row = ss*16 + l15;
      for(int g=0;g<4;g++){
        bf16x4 pk;
        for(int r=0;r<4;r++) pk[r] = (__bf16)s_[ss][g][r];
        int idx = (row*64 + g*16 + l4*4) ^ ((row & 7) << 3);
        *(bf16x4*)(&Psm[w][idx]) = pk;
      }
    }

    // O^T += V^T · P^T for both sets; V frags read ONCE, used twice
    __builtin_amdgcn_s_setprio(1);
    for(int c=0;c<2;c++){
      bf16x8 pf0, pf1;
      {
        int row0 = l15,      idx0 = (row0*64 + c*32 + l4*8) ^ ((row0 & 7) << 3);
        int row1 = 16 + l15, idx1 = (row1*64 + c*32 + l4*8) ^ ((row1 & 7) << 3);
        pf0 = *(const bf16x8*)(&Psm[w][idx0]);
        pf1 = *(const bf16x8*)(&Psm[w][idx1]);
      }
      accL[0] = __builtin_amdgcn_mfma_f32_16x16x32_bf16(ones, pf0, accL[0], 0,0,0);
      accL[1] = __builtin_amdgcn_mfma_f32_16x16x32_bf16(ones, pf1, accL[1], 0,0,0);
      for(int g=0;g<4;g++){
        int row = g*16 + l15;
        int idx = (row*64 + c*32 + l4*8) ^ ((row & 7) << 3);
        bf16x8 vf = *(const bf16x8*)(&Vsm[cur][idx]);
        accT[0][g] = __builtin_amdgcn_mfma_f32_16x16x32_bf16(vf, pf0, accT[0][g], 0,0,0);
        accT[1][g] = __builtin_amdgcn_mfma_f32_16x16x32_bf16(vf, pf1, accT[1][g], 0,0,0);
      }
    }
    __builtin_amdgcn_s_setprio(0);

    __syncthreads();
  };

  for(int t2=0; t2<16; ++t2){
    body(2*t2,   0);
    body(2*t2+1, 1);
  }

  // normalize + write O^T -> attn [B*T, H*64] bf16
  #pragma unroll
  for(int ss=0;ss<2;ss++){
    float oinv = 1.0f / accL[ss][0];
    int m = b*T_ + qt*128 + w*32 + ss*16 + l15;
    for(int g=0;g<4;g++){
      bf16x4 pk;
      for(int r=0;r<4;r++) pk[r] = (__bf16)(accT[ss][g][r] * oinv);
      *(bf16x4*)(attn_out + (size_t)m*1024 + h*64 + g*16 + l4*4) = pk;
    }
  }
}

// ---------------- final GEMM: attn[4096,1024] x WoT + bo -> fp32 out ----------------
// 64x128 tile, 1D grid 512 + XCD swizzle (m-stripes); C^T -> float4 stores
__global__ __launch_bounds__(256) void k_gemm_out(const u16* __restrict__ A,
                                                  const u16* __restrict__ BT,
                                                  const float* __restrict__ bias,
                                                  float* __restrict__ out){
  int bid = blockIdx.x;
  int sw  = (bid & 7) * 64 + (bid >> 3);     // 512 = 8 x 64
  int n0 = (sw & 7) * 128;
  int m0 = (sw >> 3) * 64;
  __shared__ u16 Asm[64*64];
  __shared__ u16 Bsm[128*64];
  int t = threadIdx.x;
  int lane = t & 63, w = t >> 6, wm = w >> 1, wn = w & 1;
  int l15 = lane & 15, l4 = lane >> 4;
  f32x4 zero = {0.f,0.f,0.f,0.f};
  f32x4 acc[2][4];
  for(int i=0;i<2;i++) for(int j=0;j<4;j++) acc[i][j] = zero;
  int srow = t >> 3, schunk = t & 7;

  for(int kt=0; kt<16; ++kt){
    __syncthreads();
    int kb = kt * 64;
    for(int i=0;i<2;i++){
      int row = i*32 + srow;
      int gch = schunk ^ (row & 7);
      gl_lds16(A  + (size_t)(m0+row)*1024 + kb + gch*8, Asm + row*64 + schunk*8);
    }
    for(int i=0;i<4;i++){
      int row = i*32 + srow;
      int gch = schunk ^ (row & 7);
      gl_lds16(BT + (size_t)(n0+row)*1024 + kb + gch*8, Bsm + row*64 + schunk*8);
    }
    __syncthreads();
    for(int c=0;c<2;c++){
      bf16x8 af[2], bfr[4];
      for(int mt=0;mt<2;mt++){
        int row = wm*32 + mt*16 + l15;
        int idx = (row*64 + c*32 + l4*8) ^ ((row & 7) << 3);
        af[mt] = *(const bf16x8*)(Asm + idx);
      }
      for(int nt=0;nt<4;nt++){
        int row = wn*64 + nt*16 + l15;
        int idx = (row*64 + c*32 + l4*8) ^ ((row & 7) << 3);
        bfr[nt] = *(const bf16x8*)(Bsm + idx);
      }
      for(int mt=0;mt<2;mt++)
        for(int nt=0;nt<4;nt++)
          acc[mt][nt] = __builtin_amdgcn_mfma_f32_16x16x32_bf16(bfr[nt], af[mt], acc[mt][nt], 0,0,0);
    }
  }
  for(int nt=0;nt<4;nt++){
    int nb = n0 + wn*64 + nt*16 + l4*4;
    float4 b4 = *(const float4*)&bias[nb];
    for(int mt=0;mt<2;mt++){
      int m = m0 + wm*32 + mt*16 + l15;
      float4 o;
      o.x = acc[mt][nt][0] + b4.x;
      o.y = acc[mt][nt][1] + b4.y;
      o.z = acc[mt][nt][2] + b4.z;
      o.w = acc[mt][nt][3] + b4.w;
      *(float4*)&out[(size_t)m*1024 + nb] = o;
    }
  }
}

extern "C" void kernel_launch(void* const* d_in, const int* in_sizes, int n_in,
                              void* d_out, int out_size, void* d_ws, size_t ws_size,
                              hipStream_t stream){
  const float* x  = (const float*)d_in[0];
  const float* Wq = (const float*)d_in[1];
  const float* bq = (const float*)d_in[2];
  const float* Wk = (const float*)d_in[3];
  const float* bk = (const float*)d_in[4];
  const float* Wv = (const float*)d_in[5];
  const float* bv = (const float*)d_in[6];
  const float* Wo = (const float*)d_in[7];
  const float* bo = (const float*)d_in[8];
  float* out = (float*)d_out;
  char* ws = (char*)d_ws;

  u16* xb  = (u16*)(ws);                    // 8 MB  : x bf16 [4096,1024]
  u16* wt  = (u16*)(ws + (8u  << 20));      // 8 MB  : WqT,WkT,WvT,WoT bf16
  u16* qkv = (u16*)(ws + (16u << 20));      // 16 MB : Q,K bf16 [BH,T,64]
  u16* vt  = (u16*)(ws + (40u << 20));      // 8 MB  : VT bf16 [BH,64,T]
  u16* at  = (u16*)(ws + (48u << 20));      // 8 MB  : attn bf16 [4096,1024]

  k_prep    <<<8192, 256, 0, stream>>>(x, xb, Wq, Wk, Wv, Wo, wt);
  k_gemm_qkv<<<768,  256, 0, stream>>>(xb, wt, bq, bk, bv, qkv, vt);
  k_attn    <<<512,  256, 0, stream>>>(qkv, qkv + (size_t)4*1024*1024, vt, at);
  k_gemm_out<<<512,  256, 0, stream>>>(at, wt + (size_t)3*1024*1024, bo, out);
}